// Round 13
// baseline (325.077 us; speedup 1.0000x reference)
//
#include <hip/hip_runtime.h>

#define N_NODES 100000
#define N_EDGES 1250000
#define D 64

#define BSHIFT 9
#define BUCKETS 196          // ceil(100000 / 512)
#define CAP 8192             // tmp capacity per bucket (mean 6378, +22 sigma)
#define CHUNK 4096           // edges per bucketA block (R11-proven)
#define PA_BLOCKS ((N_EDGES + CHUNK - 1) / CHUNK)   // 306
#define CVT_BLOCKS 718       // merged-grid blocks doing fp32->bf16 convert
#define LCAP 64              // LDS list capacity per bucket per chunk (mean 21, max<64)
#define SRT_SLACK 256        // fused reads up to ~64 slots past a segment end
#define NBLK 12500           // one wave per node-pair: 12500*4 = 50000 pairs

typedef long long ll;
typedef unsigned int uint;

// round-to-nearest-even fp32 -> bf16
__device__ __forceinline__ ushort f2bf(float f) {
    uint u = __float_as_uint(f);
    u += 0x7fffu + ((u >> 16) & 1u);
    return (ushort)(u >> 16);
}

// ---------- init: cursor[b]=b*CAP; offs[N] sentinel; zero rows (index N_NODES) ----------
__global__ void init_kernel(int* __restrict__ cursor, int* __restrict__ offs,
                            ushort* __restrict__ xb, ushort* __restrict__ hidb) {
    int t = threadIdx.x;
    if (t < BUCKETS) cursor[t] = t * CAP;
    if (t == 0) offs[N_NODES] = N_EDGES;
    if (t < 16) {   // zero row (index N_NODES) in both bf16 operands: 128 B each
        uint2 z; z.x = 0; z.y = 0;
        ((uint2*)(xb   + (ll)N_NODES * D))[t] = z;
        ((uint2*)(hidb + (ll)N_NODES * D))[t] = z;
    }
}

// ---------- pass A + cvt in one grid (R11-proven) ----------
// Blocks 0..PA_BLOCKS-1: bin edges into 196 coarse buckets. Binning loop is
// int4-vectorized: each thread issues its 2 edge-quad loads up-front (latency
// paid once, not 8x), then runs the LDS atomic+store chain from registers.
// Blocks PA_BLOCKS..: fp32->bf16 convert of x, overlapped.
__global__ __launch_bounds__(512) void bucketA_cvt_kernel(const int* __restrict__ src,
                                                          const int* __restrict__ dst,
                                                          int* __restrict__ cursor,
                                                          int* __restrict__ tmp,
                                                          const float* __restrict__ x,
                                                          ushort* __restrict__ xb) {
    int tid = threadIdx.x;
    if (blockIdx.x >= PA_BLOCKS) {
        const int n4 = N_NODES * D / 4;
        int i = (blockIdx.x - PA_BLOCKS) * 512 + tid;
        const int stride = CVT_BLOCKS * 512;
        for (; i < n4; i += stride) {
            float4 v = ((const float4*)x)[i];
            ushort4 o;
            o.x = f2bf(v.x); o.y = f2bf(v.y); o.z = f2bf(v.z); o.w = f2bf(v.w);
            ((ushort4*)xb)[i] = o;
        }
        return;
    }

    __shared__ int lcnt[BUCKETS];
    __shared__ int gbs[BUCKETS];
    __shared__ int list[BUCKETS * LCAP];   // ~49 KB
    if (tid < BUCKETS) lcnt[tid] = 0;
    __syncthreads();

    const int base = blockIdx.x * CHUNK;
    const int nE4 = min(CHUNK, N_EDGES - base) >> 2;   // CHUNK, N_EDGES mult of 4
    const int b4  = base >> 2;
    for (int i = tid; i < nE4; i += 512) {
        const int4 s4 = ((const int4*)src)[b4 + i];
        const int4 d4 = ((const int4*)dst)[b4 + i];
        int b, p;
        b = d4.x >> BSHIFT; p = atomicAdd(&lcnt[b], 1);
        list[b * LCAP + p] = s4.x | ((d4.x & 511) << 17);
        b = d4.y >> BSHIFT; p = atomicAdd(&lcnt[b], 1);
        list[b * LCAP + p] = s4.y | ((d4.y & 511) << 17);
        b = d4.z >> BSHIFT; p = atomicAdd(&lcnt[b], 1);
        list[b * LCAP + p] = s4.z | ((d4.z & 511) << 17);
        b = d4.w >> BSHIFT; p = atomicAdd(&lcnt[b], 1);
        list[b * LCAP + p] = s4.w | ((d4.w & 511) << 17);
    }
    __syncthreads();

    if (tid < BUCKETS) gbs[tid] = atomicAdd(&cursor[tid], lcnt[tid]);  // parallel
    __syncthreads();

    int wv = tid >> 6, lane = tid & 63;
    for (int b = wv; b < BUCKETS; b += 8) {        // 8 waves, fire-and-forget stores
        int c = lcnt[b];
        if (lane < c) tmp[gbs[b] + lane] = list[b * LCAP + lane];
    }
}

// ---------- pass B: per-bucket local sort -> final srt + offs (R11-proven) ----------
// tmp staged into LDS once (hist fused into the load loop); scatter reads LDS.
// Wave-shuffle scans (4 barriers).
__global__ __launch_bounds__(512) void bucketB_kernel(const int* __restrict__ cursor,
                                                      const int* __restrict__ tmp,
                                                      int* __restrict__ srt,
                                                      int* __restrict__ offs) {
    __shared__ int list[CAP];          // 32 KB: the bucket's full payload
    __shared__ int hist[512];
    __shared__ int cur[512];
    __shared__ int sbase[256];
    __shared__ int wsum[8];
    const int b = blockIdx.x, tid = threadIdx.x;
    const int wv = tid >> 6, lane = tid & 63;
    const int cbase = b * CAP;
    const int cnt = cursor[b] - cbase;

    hist[tid] = 0;
    // wave 0: exclusive scan over the 196 bucket counts (4 buckets/lane + shfl)
    if (wv == 0) {
        int c0, c1, c2, c3;
        const int q4 = lane << 2;
        c0 = (q4     < BUCKETS) ? (cursor[q4]     - (q4    ) * CAP) : 0;
        c1 = (q4 + 1 < BUCKETS) ? (cursor[q4 + 1] - (q4 + 1) * CAP) : 0;
        c2 = (q4 + 2 < BUCKETS) ? (cursor[q4 + 2] - (q4 + 2) * CAP) : 0;
        c3 = (q4 + 3 < BUCKETS) ? (cursor[q4 + 3] - (q4 + 3) * CAP) : 0;
        const int s1 = c0 + c1, sum = s1 + c2 + c3;
        int run = sum;
#pragma unroll
        for (int d = 1; d < 64; d <<= 1) {
            int t = __shfl_up(run, d);
            if (lane >= d) run += t;
        }
        const int lex = run - sum;        // exclusive prefix of this lane's group
        sbase[q4]     = lex;
        sbase[q4 + 1] = lex + c0;
        sbase[q4 + 2] = lex + s1;
        sbase[q4 + 3] = lex + s1 + c2;
    }
    __syncthreads();                      // hist zeroed + sbase ready
    const int gbase = sbase[b];

    // stage tmp -> LDS once; hist on the fly
    for (int i = tid; i < cnt; i += 512) {
        int v = tmp[cbase + i];
        list[i] = v;
        atomicAdd(&hist[v >> 17], 1);     // LDS atomic, avg 12.5/node
    }
    __syncthreads();

    // 512-wide exclusive scan: per-wave shfl inclusive scan + wave-offset add
    const int x = hist[tid];
    int v = x;
#pragma unroll
    for (int d = 1; d < 64; d <<= 1) {
        int t = __shfl_up(v, d);
        if (lane >= d) v += t;
    }
    if (lane == 63) wsum[wv] = v;
    __syncthreads();
    int woff = 0;
#pragma unroll
    for (int k = 0; k < 8; ++k) woff += (k < wv) ? wsum[k] : 0;   // LDS broadcasts
    const int excl = v + woff - x;
    cur[tid] = excl;

    const int node0 = b << BSHIFT;
    const int nloc = min(512, N_NODES - node0);
    if (tid < nloc) offs[node0 + tid] = gbase + excl;   // coalesced
    __syncthreads();

    // scatter from LDS (no global re-read); stores hit the bucket's ~25KB window
    for (int i = tid; i < cnt; i += 512) {
        int t = list[i];
        int ln = t >> 17;
        int p = atomicAdd(&cur[ln], 1);
        srt[gbase + p] = t & 0x1FFFF;
    }
}

// ---------- fused pull + linear: bf16 gather, ONE node-pair per wave ----------
// R11 body (VGPR=64, 56.2us/layer) minus the grid-stride loop: NBLK*4 waves =
// 50000 = exactly one pair per wave. Degree-imbalanced pairs no longer stack
// on the same wave — the HW scheduler absorbs the tail. Protect VGPR<=64.
#define UACC(V, AX, AY, AZ, AW)                               \
    AX += __uint_as_float((V).x << 16);                       \
    AY += __uint_as_float((V).x & 0xffff0000u);               \
    AZ += __uint_as_float((V).y << 16);                       \
    AW += __uint_as_float((V).y & 0xffff0000u);

template<int EMIT>
__global__ __launch_bounds__(256) void fused_layer(const ushort* __restrict__ hb,
                                                   const int* __restrict__ offs,
                                                   const int* __restrict__ srt,
                                                   const float* __restrict__ W1,
                                                   const float* __restrict__ b1,
                                                   float* __restrict__ out,
                                                   ushort* __restrict__ outb) {
    __shared__ __align__(16) float rbA[4][64];
    __shared__ __align__(16) float rbB[4][64];
    const int tid  = threadIdx.x;
    const int lane = tid & 63;
    const int wid  = tid >> 6;
    const int g    = lane >> 4;          // gather group 0..3
    const int sub  = lane & 15;          // uint2 (4 bf16) within row; also srt slot
    const uint roff = (uint)sub << 3;    // byte offset within 128-B row
    const int goff = g << 2;
    const int p    = blockIdx.x * 4 + wid;   // this wave's node pair
    const char* hbase = (const char*)hb;

    const float4* wrow = (const float4*)(W1 + lane * D);
    const float bj = b1[lane];

    if (p >= (N_NODES >> 1)) return;
    const int nA = p << 1;
    const int2 o2 = *(const int2*)(offs + nA);   // begA, endA(=begB)
    const int begA = o2.x;
    const int endA = o2.y;
    const int endB = offs[nA + 2];               // offs[N] sentinel

    float aAx = 0.f, aAy = 0.f, aAz = 0.f, aAw = 0.f;
    float aBx = 0.f, aBy = 0.f, aBz = 0.f, aBw = 0.f;

    int ebA = begA, ebB = endA;
    while (ebA < endA || ebB < endB) {
        // one coalesced 16-slot srt load per node (slack past N_EDGES);
        // per-slot sentinel for slots beyond the segment end
        int siA = srt[ebA + sub];
        int siB = srt[ebB + sub];
        siA = (ebA + sub < endA) ? siA : N_NODES;
        siB = (ebB + sub < endB) ? siB : N_NODES;
        const int iA0 = __shfl(siA, goff);
        const int iA1 = __shfl(siA, goff + 1);
        const int iA2 = __shfl(siA, goff + 2);
        const int iA3 = __shfl(siA, goff + 3);
        const int iB0 = __shfl(siB, goff);
        const int iB1 = __shfl(siB, goff + 1);
        const int iB2 = __shfl(siB, goff + 2);
        const int iB3 = __shfl(siB, goff + 3);
        const uint2 vA0 = *(const uint2*)(hbase + (((uint)iA0 << 7) + roff));
        const uint2 vA1 = *(const uint2*)(hbase + (((uint)iA1 << 7) + roff));
        const uint2 vA2 = *(const uint2*)(hbase + (((uint)iA2 << 7) + roff));
        const uint2 vA3 = *(const uint2*)(hbase + (((uint)iA3 << 7) + roff));
        const uint2 vB0 = *(const uint2*)(hbase + (((uint)iB0 << 7) + roff));
        const uint2 vB1 = *(const uint2*)(hbase + (((uint)iB1 << 7) + roff));
        const uint2 vB2 = *(const uint2*)(hbase + (((uint)iB2 << 7) + roff));
        const uint2 vB3 = *(const uint2*)(hbase + (((uint)iB3 << 7) + roff));
        UACC(vA0, aAx, aAy, aAz, aAw);
        UACC(vA1, aAx, aAy, aAz, aAw);
        UACC(vA2, aAx, aAy, aAz, aAw);
        UACC(vA3, aAx, aAy, aAz, aAw);
        UACC(vB0, aBx, aBy, aBz, aBw);
        UACC(vB1, aBx, aBy, aBz, aBw);
        UACC(vB2, aBx, aBy, aBz, aBw);
        UACC(vB3, aBx, aBy, aBz, aBw);
        ebA += 16; ebB += 16;
    }

    // cross-group reduce: after xor16+xor32 every lane holds the full sum
    aAx += __shfl_xor(aAx, 16); aAy += __shfl_xor(aAy, 16);
    aAz += __shfl_xor(aAz, 16); aAw += __shfl_xor(aAw, 16);
    aBx += __shfl_xor(aBx, 16); aBy += __shfl_xor(aBy, 16);
    aBz += __shfl_xor(aBz, 16); aBw += __shfl_xor(aBw, 16);
    aAx += __shfl_xor(aAx, 32); aAy += __shfl_xor(aAy, 32);
    aAz += __shfl_xor(aAz, 32); aAw += __shfl_xor(aAw, 32);
    aBx += __shfl_xor(aBx, 32); aBy += __shfl_xor(aBy, 32);
    aBz += __shfl_xor(aBz, 32); aBw += __shfl_xor(aBw, 32);

    if (g == 0) {
        float4 t; t.x = aAx; t.y = aAy; t.z = aAz; t.w = aAw;
        *((float4*)rbA[wid] + sub) = t;     // lanes 0-15 consecutive: conflict-free
    }
    if (g == 1) {
        float4 t; t.x = aBx; t.y = aBy; t.z = aBz; t.w = aBw;
        *((float4*)rbB[wid] + sub) = t;
    }
    // wave-internal LDS RAW: compiler inserts lgkmcnt wait; no barrier needed

    float oA = bj, oB = bj;
    const float4* ra = (const float4*)rbA[wid];
    const float4* rb = (const float4*)rbB[wid];
#pragma unroll
    for (int k4 = 0; k4 < 16; ++k4) {
        const float4 w  = wrow[k4];          // L1-resident (16KB), per-lane row
        const float4 rA = ra[k4];            // LDS broadcast, conflict-free
        const float4 rB = rb[k4];
        oA += rA.x * w.x + rA.y * w.y + rA.z * w.z + rA.w * w.w;
        oB += rB.x * w.x + rB.y * w.y + rB.z * w.z + rB.w * w.w;
    }
    __builtin_nontemporal_store(oA, out + (ll)nA * D + lane);
    __builtin_nontemporal_store(oB, out + (ll)(nA + 1) * D + lane);
    if (EMIT) {
        outb[(ll)nA * D + lane]       = f2bf(oA);   // plain store: keep L2-hot
        outb[(ll)(nA + 1) * D + lane] = f2bf(oB);
    }
}

extern "C" void kernel_launch(void* const* d_in, const int* in_sizes, int n_in,
                              void* d_out, int out_size, void* d_ws, size_t ws_size,
                              hipStream_t stream) {
    const float* x  = (const float*)d_in[0];   // [N, D]
    const int* edge = (const int*)d_in[1];     // [2, E]: src row then dst row
    const float* W1 = (const float*)d_in[2];   // [D, D]
    const float* b1 = (const float*)d_in[3];   // [D]

    const int* src = edge;
    const int* dst = edge + N_EDGES;

    float* out = (float*)d_out;                    // output 0: [N, D]
    float* hid = (float*)d_out + (ll)N_NODES * D;  // output 1: [N, D]

    // xb (bf16 copy of x, N+1 rows incl zero row) lives in the `out` region:
    // only read during layer 1 (which writes hid); layer 2 overwrites out fully.
    ushort* xb = (ushort*)d_out;                   // 12.81 MB < 25.6 MB

    // workspace layout (~24.7 MiB; 25.6 MB proven available)
    char* ws = (char*)d_ws;
    int* cursor = (int*)ws;  ws += 1024;                                          // [196]
    int* offs   = (int*)ws;  ws += ((size_t)(N_NODES + 1) * 4 + 255) & ~255ull;   // [N+1]
    int* srt    = (int*)ws;  ws += ((size_t)(N_EDGES + SRT_SLACK) * 4 + 255) & ~255ull;
    ushort* hidb = (ushort*)ws; ws += (size_t)(N_NODES + 1) * D * 2;              // [(N+1),D]
    int* tmp    = (int*)ws;                                                       // [196*CAP]

    // ---- build CSR (bucket sort) with cvt overlapped in the same grid ----
    init_kernel<<<1, 256, 0, stream>>>(cursor, offs, xb, hidb);
    bucketA_cvt_kernel<<<PA_BLOCKS + CVT_BLOCKS, 512, 0, stream>>>(src, dst, cursor,
                                                                   tmp, x, xb);
    bucketB_kernel<<<BUCKETS, 512, 0, stream>>>(cursor, tmp, srt, offs);

    // ---- layer 1: hid = segsum(x) @ W1^T + b1 (bf16 gather; emits bf16 hid) ----
    fused_layer<1><<<NBLK, 256, 0, stream>>>(xb, offs, srt, W1, b1, hid, hidb);
    // ---- layer 2: out = segsum(hid) @ W1^T + b1 (bf16 gather) ----
    fused_layer<0><<<NBLK, 256, 0, stream>>>(hidb, offs, srt, W1, b1, out, (ushort*)nullptr);
}

// Round 14
// 235.212 us; speedup vs baseline: 1.3821x; 1.3821x over previous
//
#include <hip/hip_runtime.h>

#define N_NODES 100000
#define N_EDGES 1250000
#define D 64

#define BSHIFT 9
#define BUCKETS 196          // ceil(100000 / 512)
#define CAP 8192             // tmp capacity per bucket (mean 6378, +22 sigma)
#define CHUNK 4096           // edges per bucketA block (R11-proven)
#define PA_BLOCKS ((N_EDGES + CHUNK - 1) / CHUNK)   // 306
#define CVT_BLOCKS 718       // merged-grid blocks doing fp32->bf16 convert
#define LCAP 64              // LDS list capacity per bucket per chunk (mean 21, max<64)
#define SRT_SLACK 256        // fused reads up to ~64 slots past a segment end
#define NBLK 4096            // ~3 pairs/wave: loop kept (forces load liveness), tail halved

typedef long long ll;
typedef unsigned int uint;

// round-to-nearest-even fp32 -> bf16
__device__ __forceinline__ ushort f2bf(float f) {
    uint u = __float_as_uint(f);
    u += 0x7fffu + ((u >> 16) & 1u);
    return (ushort)(u >> 16);
}

// ---------- init: cursor[b]=b*CAP; offs[N] sentinel; zero rows (index N_NODES) ----------
__global__ void init_kernel(int* __restrict__ cursor, int* __restrict__ offs,
                            ushort* __restrict__ xb, ushort* __restrict__ hidb) {
    int t = threadIdx.x;
    if (t < BUCKETS) cursor[t] = t * CAP;
    if (t == 0) offs[N_NODES] = N_EDGES;
    if (t < 16) {   // zero row (index N_NODES) in both bf16 operands: 128 B each
        uint2 z; z.x = 0; z.y = 0;
        ((uint2*)(xb   + (ll)N_NODES * D))[t] = z;
        ((uint2*)(hidb + (ll)N_NODES * D))[t] = z;
    }
}

// ---------- pass A + cvt in one grid (R11-proven) ----------
__global__ __launch_bounds__(512) void bucketA_cvt_kernel(const int* __restrict__ src,
                                                          const int* __restrict__ dst,
                                                          int* __restrict__ cursor,
                                                          int* __restrict__ tmp,
                                                          const float* __restrict__ x,
                                                          ushort* __restrict__ xb) {
    int tid = threadIdx.x;
    if (blockIdx.x >= PA_BLOCKS) {
        const int n4 = N_NODES * D / 4;
        int i = (blockIdx.x - PA_BLOCKS) * 512 + tid;
        const int stride = CVT_BLOCKS * 512;
        for (; i < n4; i += stride) {
            float4 v = ((const float4*)x)[i];
            ushort4 o;
            o.x = f2bf(v.x); o.y = f2bf(v.y); o.z = f2bf(v.z); o.w = f2bf(v.w);
            ((ushort4*)xb)[i] = o;
        }
        return;
    }

    __shared__ int lcnt[BUCKETS];
    __shared__ int gbs[BUCKETS];
    __shared__ int list[BUCKETS * LCAP];   // ~49 KB
    if (tid < BUCKETS) lcnt[tid] = 0;
    __syncthreads();

    const int base = blockIdx.x * CHUNK;
    const int nE4 = min(CHUNK, N_EDGES - base) >> 2;   // CHUNK, N_EDGES mult of 4
    const int b4  = base >> 2;
    for (int i = tid; i < nE4; i += 512) {
        const int4 s4 = ((const int4*)src)[b4 + i];
        const int4 d4 = ((const int4*)dst)[b4 + i];
        int b, p;
        b = d4.x >> BSHIFT; p = atomicAdd(&lcnt[b], 1);
        list[b * LCAP + p] = s4.x | ((d4.x & 511) << 17);
        b = d4.y >> BSHIFT; p = atomicAdd(&lcnt[b], 1);
        list[b * LCAP + p] = s4.y | ((d4.y & 511) << 17);
        b = d4.z >> BSHIFT; p = atomicAdd(&lcnt[b], 1);
        list[b * LCAP + p] = s4.z | ((d4.z & 511) << 17);
        b = d4.w >> BSHIFT; p = atomicAdd(&lcnt[b], 1);
        list[b * LCAP + p] = s4.w | ((d4.w & 511) << 17);
    }
    __syncthreads();

    if (tid < BUCKETS) gbs[tid] = atomicAdd(&cursor[tid], lcnt[tid]);  // parallel
    __syncthreads();

    int wv = tid >> 6, lane = tid & 63;
    for (int b = wv; b < BUCKETS; b += 8) {        // 8 waves, fire-and-forget stores
        int c = lcnt[b];
        if (lane < c) tmp[gbs[b] + lane] = list[b * LCAP + lane];
    }
}

// ---------- pass B: per-bucket local sort -> final srt + offs (R11-proven) ----------
__global__ __launch_bounds__(512) void bucketB_kernel(const int* __restrict__ cursor,
                                                      const int* __restrict__ tmp,
                                                      int* __restrict__ srt,
                                                      int* __restrict__ offs) {
    __shared__ int list[CAP];          // 32 KB: the bucket's full payload
    __shared__ int hist[512];
    __shared__ int cur[512];
    __shared__ int sbase[256];
    __shared__ int wsum[8];
    const int b = blockIdx.x, tid = threadIdx.x;
    const int wv = tid >> 6, lane = tid & 63;
    const int cbase = b * CAP;
    const int cnt = cursor[b] - cbase;

    hist[tid] = 0;
    // wave 0: exclusive scan over the 196 bucket counts (4 buckets/lane + shfl)
    if (wv == 0) {
        int c0, c1, c2, c3;
        const int q4 = lane << 2;
        c0 = (q4     < BUCKETS) ? (cursor[q4]     - (q4    ) * CAP) : 0;
        c1 = (q4 + 1 < BUCKETS) ? (cursor[q4 + 1] - (q4 + 1) * CAP) : 0;
        c2 = (q4 + 2 < BUCKETS) ? (cursor[q4 + 2] - (q4 + 2) * CAP) : 0;
        c3 = (q4 + 3 < BUCKETS) ? (cursor[q4 + 3] - (q4 + 3) * CAP) : 0;
        const int s1 = c0 + c1, sum = s1 + c2 + c3;
        int run = sum;
#pragma unroll
        for (int d = 1; d < 64; d <<= 1) {
            int t = __shfl_up(run, d);
            if (lane >= d) run += t;
        }
        const int lex = run - sum;        // exclusive prefix of this lane's group
        sbase[q4]     = lex;
        sbase[q4 + 1] = lex + c0;
        sbase[q4 + 2] = lex + s1;
        sbase[q4 + 3] = lex + s1 + c2;
    }
    __syncthreads();                      // hist zeroed + sbase ready
    const int gbase = sbase[b];

    // stage tmp -> LDS once; hist on the fly
    for (int i = tid; i < cnt; i += 512) {
        int v = tmp[cbase + i];
        list[i] = v;
        atomicAdd(&hist[v >> 17], 1);     // LDS atomic, avg 12.5/node
    }
    __syncthreads();

    // 512-wide exclusive scan: per-wave shfl inclusive scan + wave-offset add
    const int x = hist[tid];
    int v = x;
#pragma unroll
    for (int d = 1; d < 64; d <<= 1) {
        int t = __shfl_up(v, d);
        if (lane >= d) v += t;
    }
    if (lane == 63) wsum[wv] = v;
    __syncthreads();
    int woff = 0;
#pragma unroll
    for (int k = 0; k < 8; ++k) woff += (k < wv) ? wsum[k] : 0;   // LDS broadcasts
    const int excl = v + woff - x;
    cur[tid] = excl;

    const int node0 = b << BSHIFT;
    const int nloc = min(512, N_NODES - node0);
    if (tid < nloc) offs[node0 + tid] = gbase + excl;   // coalesced
    __syncthreads();

    // scatter from LDS (no global re-read); stores hit the bucket's ~25KB window
    for (int i = tid; i < cnt; i += 512) {
        int t = list[i];
        int ln = t >> 17;
        int p = atomicAdd(&cur[ln], 1);
        srt[gbase + p] = t & 0x1FFFF;
    }
}

// ---------- fused pull + linear: bf16 gather, node-pair, read-time sentinel ----------
// EXACT R11 body (measured: VGPR=64, occ 34.8%, 56.2us/layer). The grid-stride
// loop is load-liveness scaffolding: without it the compiler minimizes to
// VGPR=36 and SERIALIZES the 16-load batch (R13: 116us despite 67% occ).
// Only NBLK changed (2048->4096): ~3 pairs/wave, halves degree-tail stacking.
#define UACC(V, AX, AY, AZ, AW)                               \
    AX += __uint_as_float((V).x << 16);                       \
    AY += __uint_as_float((V).x & 0xffff0000u);               \
    AZ += __uint_as_float((V).y << 16);                       \
    AW += __uint_as_float((V).y & 0xffff0000u);

template<int EMIT>
__global__ __launch_bounds__(256) void fused_layer(const ushort* __restrict__ hb,
                                                   const int* __restrict__ offs,
                                                   const int* __restrict__ srt,
                                                   const float* __restrict__ W1,
                                                   const float* __restrict__ b1,
                                                   float* __restrict__ out,
                                                   ushort* __restrict__ outb) {
    __shared__ __align__(16) float rbA[4][64];
    __shared__ __align__(16) float rbB[4][64];
    const int tid  = threadIdx.x;
    const int lane = tid & 63;
    const int wid  = tid >> 6;
    const int g    = lane >> 4;          // gather group 0..3
    const int sub  = lane & 15;          // uint2 (4 bf16) within row; also srt slot
    const uint roff = (uint)sub << 3;    // byte offset within 128-B row
    const int goff = g << 2;
    const int gw   = blockIdx.x * 4 + wid;
    const int GW   = NBLK * 4;
    const char* hbase = (const char*)hb;

    const float4* wrow = (const float4*)(W1 + lane * D);
    const float bj = b1[lane];

    for (int p = gw; p < (N_NODES >> 1); p += GW) {
        const int nA = p << 1;
        const int2 o2 = *(const int2*)(offs + nA);   // begA, endA(=begB)
        const int begA = o2.x;
        const int endA = o2.y;
        const int endB = offs[nA + 2];               // offs[N] sentinel

        float aAx = 0.f, aAy = 0.f, aAz = 0.f, aAw = 0.f;
        float aBx = 0.f, aBy = 0.f, aBz = 0.f, aBw = 0.f;

        int ebA = begA, ebB = endA;
        while (ebA < endA || ebB < endB) {
            // one coalesced 16-slot srt load per node (slack past N_EDGES);
            // per-slot sentinel for slots beyond the segment end
            int siA = srt[ebA + sub];
            int siB = srt[ebB + sub];
            siA = (ebA + sub < endA) ? siA : N_NODES;
            siB = (ebB + sub < endB) ? siB : N_NODES;
            const int iA0 = __shfl(siA, goff);
            const int iA1 = __shfl(siA, goff + 1);
            const int iA2 = __shfl(siA, goff + 2);
            const int iA3 = __shfl(siA, goff + 3);
            const int iB0 = __shfl(siB, goff);
            const int iB1 = __shfl(siB, goff + 1);
            const int iB2 = __shfl(siB, goff + 2);
            const int iB3 = __shfl(siB, goff + 3);
            const uint2 vA0 = *(const uint2*)(hbase + (((uint)iA0 << 7) + roff));
            const uint2 vA1 = *(const uint2*)(hbase + (((uint)iA1 << 7) + roff));
            const uint2 vA2 = *(const uint2*)(hbase + (((uint)iA2 << 7) + roff));
            const uint2 vA3 = *(const uint2*)(hbase + (((uint)iA3 << 7) + roff));
            const uint2 vB0 = *(const uint2*)(hbase + (((uint)iB0 << 7) + roff));
            const uint2 vB1 = *(const uint2*)(hbase + (((uint)iB1 << 7) + roff));
            const uint2 vB2 = *(const uint2*)(hbase + (((uint)iB2 << 7) + roff));
            const uint2 vB3 = *(const uint2*)(hbase + (((uint)iB3 << 7) + roff));
            UACC(vA0, aAx, aAy, aAz, aAw);
            UACC(vA1, aAx, aAy, aAz, aAw);
            UACC(vA2, aAx, aAy, aAz, aAw);
            UACC(vA3, aAx, aAy, aAz, aAw);
            UACC(vB0, aBx, aBy, aBz, aBw);
            UACC(vB1, aBx, aBy, aBz, aBw);
            UACC(vB2, aBx, aBy, aBz, aBw);
            UACC(vB3, aBx, aBy, aBz, aBw);
            ebA += 16; ebB += 16;
        }

        // cross-group reduce: after xor16+xor32 every lane holds the full sum
        aAx += __shfl_xor(aAx, 16); aAy += __shfl_xor(aAy, 16);
        aAz += __shfl_xor(aAz, 16); aAw += __shfl_xor(aAw, 16);
        aBx += __shfl_xor(aBx, 16); aBy += __shfl_xor(aBy, 16);
        aBz += __shfl_xor(aBz, 16); aBw += __shfl_xor(aBw, 16);
        aAx += __shfl_xor(aAx, 32); aAy += __shfl_xor(aAy, 32);
        aAz += __shfl_xor(aAz, 32); aAw += __shfl_xor(aAw, 32);
        aBx += __shfl_xor(aBx, 32); aBy += __shfl_xor(aBy, 32);
        aBz += __shfl_xor(aBz, 32); aBw += __shfl_xor(aBw, 32);

        if (g == 0) {
            float4 t; t.x = aAx; t.y = aAy; t.z = aAz; t.w = aAw;
            *((float4*)rbA[wid] + sub) = t;     // lanes 0-15 consecutive: conflict-free
        }
        if (g == 1) {
            float4 t; t.x = aBx; t.y = aBy; t.z = aBz; t.w = aBw;
            *((float4*)rbB[wid] + sub) = t;
        }
        // wave-internal LDS RAW: compiler inserts lgkmcnt wait; no barrier needed

        float oA = bj, oB = bj;
        const float4* ra = (const float4*)rbA[wid];
        const float4* rb = (const float4*)rbB[wid];
#pragma unroll
        for (int k4 = 0; k4 < 16; ++k4) {
            const float4 w  = wrow[k4];          // L1-resident (16KB), per-lane row
            const float4 rA = ra[k4];            // LDS broadcast, conflict-free
            const float4 rB = rb[k4];
            oA += rA.x * w.x + rA.y * w.y + rA.z * w.z + rA.w * w.w;
            oB += rB.x * w.x + rB.y * w.y + rB.z * w.z + rB.w * w.w;
        }
        __builtin_nontemporal_store(oA, out + (ll)nA * D + lane);
        __builtin_nontemporal_store(oB, out + (ll)(nA + 1) * D + lane);
        if (EMIT) {
            outb[(ll)nA * D + lane]       = f2bf(oA);   // plain store: keep L2-hot
            outb[(ll)(nA + 1) * D + lane] = f2bf(oB);
        }
    }
}

extern "C" void kernel_launch(void* const* d_in, const int* in_sizes, int n_in,
                              void* d_out, int out_size, void* d_ws, size_t ws_size,
                              hipStream_t stream) {
    const float* x  = (const float*)d_in[0];   // [N, D]
    const int* edge = (const int*)d_in[1];     // [2, E]: src row then dst row
    const float* W1 = (const float*)d_in[2];   // [D, D]
    const float* b1 = (const float*)d_in[3];   // [D]

    const int* src = edge;
    const int* dst = edge + N_EDGES;

    float* out = (float*)d_out;                    // output 0: [N, D]
    float* hid = (float*)d_out + (ll)N_NODES * D;  // output 1: [N, D]

    // xb (bf16 copy of x, N+1 rows incl zero row) lives in the `out` region:
    // only read during layer 1 (which writes hid); layer 2 overwrites out fully.
    ushort* xb = (ushort*)d_out;                   // 12.81 MB < 25.6 MB

    // workspace layout (~24.7 MiB; 25.6 MB proven available)
    char* ws = (char*)d_ws;
    int* cursor = (int*)ws;  ws += 1024;                                          // [196]
    int* offs   = (int*)ws;  ws += ((size_t)(N_NODES + 1) * 4 + 255) & ~255ull;   // [N+1]
    int* srt    = (int*)ws;  ws += ((size_t)(N_EDGES + SRT_SLACK) * 4 + 255) & ~255ull;
    ushort* hidb = (ushort*)ws; ws += (size_t)(N_NODES + 1) * D * 2;              // [(N+1),D]
    int* tmp    = (int*)ws;                                                       // [196*CAP]

    // ---- build CSR (bucket sort) with cvt overlapped in the same grid ----
    init_kernel<<<1, 256, 0, stream>>>(cursor, offs, xb, hidb);
    bucketA_cvt_kernel<<<PA_BLOCKS + CVT_BLOCKS, 512, 0, stream>>>(src, dst, cursor,
                                                                   tmp, x, xb);
    bucketB_kernel<<<BUCKETS, 512, 0, stream>>>(cursor, tmp, srt, offs);

    // ---- layer 1: hid = segsum(x) @ W1^T + b1 (bf16 gather; emits bf16 hid) ----
    fused_layer<1><<<NBLK, 256, 0, stream>>>(xb, offs, srt, W1, b1, hid, hidb);
    // ---- layer 2: out = segsum(hid) @ W1^T + b1 (bf16 gather) ----
    fused_layer<0><<<NBLK, 256, 0, stream>>>(hidb, offs, srt, W1, b1, out, (ushort*)nullptr);
}

// Round 15
// 209.306 us; speedup vs baseline: 1.5531x; 1.1238x over previous
//
#include <hip/hip_runtime.h>

#define N_NODES 100000
#define N_EDGES 1250000
#define D 64

#define BSHIFT 9
#define BUCKETS 196          // ceil(100000 / 512)
#define CAP 8192             // tmp capacity per bucket (mean 6378, +22 sigma)
#define CHUNK 4096           // edges per bucketA block (R11-proven)
#define PA_BLOCKS ((N_EDGES + CHUNK - 1) / CHUNK)   // 306
#define CVT_BLOCKS 718       // merged-grid blocks doing fp32->bf16 convert
#define LCAP 64              // LDS list capacity per bucket per chunk (mean 21, max<64)
#define SRT_SLACK 256        // fused reads up to ~64 slots past a segment end
#define NBLK 2048            // R11-proven: ~6 pairs/wave (4096 regressed 27%, R14)

typedef long long ll;
typedef unsigned int uint;

// round-to-nearest-even fp32 -> bf16
__device__ __forceinline__ ushort f2bf(float f) {
    uint u = __float_as_uint(f);
    u += 0x7fffu + ((u >> 16) & 1u);
    return (ushort)(u >> 16);
}

// ---------- init: cursor[b]=b*CAP; offs[N] sentinel; zero rows (index N_NODES) ----------
__global__ void init_kernel(int* __restrict__ cursor, int* __restrict__ offs,
                            ushort* __restrict__ xb, ushort* __restrict__ hidb) {
    int t = threadIdx.x;
    if (t < BUCKETS) cursor[t] = t * CAP;
    if (t == 0) offs[N_NODES] = N_EDGES;
    if (t < 16) {   // zero row (index N_NODES) in both bf16 operands: 128 B each
        uint2 z; z.x = 0; z.y = 0;
        ((uint2*)(xb   + (ll)N_NODES * D))[t] = z;
        ((uint2*)(hidb + (ll)N_NODES * D))[t] = z;
    }
}

// ---------- pass A + cvt in one grid (R11-proven) ----------
// Blocks 0..PA_BLOCKS-1: bin edges into 196 coarse buckets. Binning loop is
// int4-vectorized: each thread issues its 2 edge-quad loads up-front (latency
// paid once, not 8x), then runs the LDS atomic+store chain from registers.
// Blocks PA_BLOCKS..: fp32->bf16 convert of x, overlapped.
__global__ __launch_bounds__(512) void bucketA_cvt_kernel(const int* __restrict__ src,
                                                          const int* __restrict__ dst,
                                                          int* __restrict__ cursor,
                                                          int* __restrict__ tmp,
                                                          const float* __restrict__ x,
                                                          ushort* __restrict__ xb) {
    int tid = threadIdx.x;
    if (blockIdx.x >= PA_BLOCKS) {
        const int n4 = N_NODES * D / 4;
        int i = (blockIdx.x - PA_BLOCKS) * 512 + tid;
        const int stride = CVT_BLOCKS * 512;
        for (; i < n4; i += stride) {
            float4 v = ((const float4*)x)[i];
            ushort4 o;
            o.x = f2bf(v.x); o.y = f2bf(v.y); o.z = f2bf(v.z); o.w = f2bf(v.w);
            ((ushort4*)xb)[i] = o;
        }
        return;
    }

    __shared__ int lcnt[BUCKETS];
    __shared__ int gbs[BUCKETS];
    __shared__ int list[BUCKETS * LCAP];   // ~49 KB
    if (tid < BUCKETS) lcnt[tid] = 0;
    __syncthreads();

    const int base = blockIdx.x * CHUNK;
    const int nE4 = min(CHUNK, N_EDGES - base) >> 2;   // CHUNK, N_EDGES mult of 4
    const int b4  = base >> 2;
    for (int i = tid; i < nE4; i += 512) {
        const int4 s4 = ((const int4*)src)[b4 + i];
        const int4 d4 = ((const int4*)dst)[b4 + i];
        int b, p;
        b = d4.x >> BSHIFT; p = atomicAdd(&lcnt[b], 1);
        list[b * LCAP + p] = s4.x | ((d4.x & 511) << 17);
        b = d4.y >> BSHIFT; p = atomicAdd(&lcnt[b], 1);
        list[b * LCAP + p] = s4.y | ((d4.y & 511) << 17);
        b = d4.z >> BSHIFT; p = atomicAdd(&lcnt[b], 1);
        list[b * LCAP + p] = s4.z | ((d4.z & 511) << 17);
        b = d4.w >> BSHIFT; p = atomicAdd(&lcnt[b], 1);
        list[b * LCAP + p] = s4.w | ((d4.w & 511) << 17);
    }
    __syncthreads();

    if (tid < BUCKETS) gbs[tid] = atomicAdd(&cursor[tid], lcnt[tid]);  // parallel
    __syncthreads();

    int wv = tid >> 6, lane = tid & 63;
    for (int b = wv; b < BUCKETS; b += 8) {        // 8 waves, fire-and-forget stores
        int c = lcnt[b];
        if (lane < c) tmp[gbs[b] + lane] = list[b * LCAP + lane];
    }
}

// ---------- pass B: per-bucket local sort -> final srt + offs (R11-proven) ----------
// tmp staged into LDS once (hist fused into the load loop); scatter reads LDS.
// Wave-shuffle scans (4 barriers).
__global__ __launch_bounds__(512) void bucketB_kernel(const int* __restrict__ cursor,
                                                      const int* __restrict__ tmp,
                                                      int* __restrict__ srt,
                                                      int* __restrict__ offs) {
    __shared__ int list[CAP];          // 32 KB: the bucket's full payload
    __shared__ int hist[512];
    __shared__ int cur[512];
    __shared__ int sbase[256];
    __shared__ int wsum[8];
    const int b = blockIdx.x, tid = threadIdx.x;
    const int wv = tid >> 6, lane = tid & 63;
    const int cbase = b * CAP;
    const int cnt = cursor[b] - cbase;

    hist[tid] = 0;
    // wave 0: exclusive scan over the 196 bucket counts (4 buckets/lane + shfl)
    if (wv == 0) {
        int c0, c1, c2, c3;
        const int q4 = lane << 2;
        c0 = (q4     < BUCKETS) ? (cursor[q4]     - (q4    ) * CAP) : 0;
        c1 = (q4 + 1 < BUCKETS) ? (cursor[q4 + 1] - (q4 + 1) * CAP) : 0;
        c2 = (q4 + 2 < BUCKETS) ? (cursor[q4 + 2] - (q4 + 2) * CAP) : 0;
        c3 = (q4 + 3 < BUCKETS) ? (cursor[q4 + 3] - (q4 + 3) * CAP) : 0;
        const int s1 = c0 + c1, sum = s1 + c2 + c3;
        int run = sum;
#pragma unroll
        for (int d = 1; d < 64; d <<= 1) {
            int t = __shfl_up(run, d);
            if (lane >= d) run += t;
        }
        const int lex = run - sum;        // exclusive prefix of this lane's group
        sbase[q4]     = lex;
        sbase[q4 + 1] = lex + c0;
        sbase[q4 + 2] = lex + s1;
        sbase[q4 + 3] = lex + s1 + c2;
    }
    __syncthreads();                      // hist zeroed + sbase ready
    const int gbase = sbase[b];

    // stage tmp -> LDS once; hist on the fly
    for (int i = tid; i < cnt; i += 512) {
        int v = tmp[cbase + i];
        list[i] = v;
        atomicAdd(&hist[v >> 17], 1);     // LDS atomic, avg 12.5/node
    }
    __syncthreads();

    // 512-wide exclusive scan: per-wave shfl inclusive scan + wave-offset add
    const int x = hist[tid];
    int v = x;
#pragma unroll
    for (int d = 1; d < 64; d <<= 1) {
        int t = __shfl_up(v, d);
        if (lane >= d) v += t;
    }
    if (lane == 63) wsum[wv] = v;
    __syncthreads();
    int woff = 0;
#pragma unroll
    for (int k = 0; k < 8; ++k) woff += (k < wv) ? wsum[k] : 0;   // LDS broadcasts
    const int excl = v + woff - x;
    cur[tid] = excl;

    const int node0 = b << BSHIFT;
    const int nloc = min(512, N_NODES - node0);
    if (tid < nloc) offs[node0 + tid] = gbase + excl;   // coalesced
    __syncthreads();

    // scatter from LDS (no global re-read); stores hit the bucket's ~25KB window
    for (int i = tid; i < cnt; i += 512) {
        int t = list[i];
        int ln = t >> 17;
        int p = atomicAdd(&cur[ln], 1);
        srt[gbase + p] = t & 0x1FFFF;
    }
}

// ---------- fused pull + linear: bf16 gather, node-pair, read-time sentinel ----------
// EXACT R11 configuration (measured twice: 56.2-57.3us/layer, VGPR=64, occ
// ~35%). The grid-stride loop is load-liveness scaffolding: without it the
// compiler minimizes to VGPR=36 and serializes the 16-load batch (R13).
// NBLK=2048 (~6 pairs/wave) is measured-optimal (4096 -> +27%, R14).
#define UACC(V, AX, AY, AZ, AW)                               \
    AX += __uint_as_float((V).x << 16);                       \
    AY += __uint_as_float((V).x & 0xffff0000u);               \
    AZ += __uint_as_float((V).y << 16);                       \
    AW += __uint_as_float((V).y & 0xffff0000u);

template<int EMIT>
__global__ __launch_bounds__(256) void fused_layer(const ushort* __restrict__ hb,
                                                   const int* __restrict__ offs,
                                                   const int* __restrict__ srt,
                                                   const float* __restrict__ W1,
                                                   const float* __restrict__ b1,
                                                   float* __restrict__ out,
                                                   ushort* __restrict__ outb) {
    __shared__ __align__(16) float rbA[4][64];
    __shared__ __align__(16) float rbB[4][64];
    const int tid  = threadIdx.x;
    const int lane = tid & 63;
    const int wid  = tid >> 6;
    const int g    = lane >> 4;          // gather group 0..3
    const int sub  = lane & 15;          // uint2 (4 bf16) within row; also srt slot
    const uint roff = (uint)sub << 3;    // byte offset within 128-B row
    const int goff = g << 2;
    const int gw   = blockIdx.x * 4 + wid;
    const int GW   = NBLK * 4;
    const char* hbase = (const char*)hb;

    const float4* wrow = (const float4*)(W1 + lane * D);
    const float bj = b1[lane];

    for (int p = gw; p < (N_NODES >> 1); p += GW) {
        const int nA = p << 1;
        const int2 o2 = *(const int2*)(offs + nA);   // begA, endA(=begB)
        const int begA = o2.x;
        const int endA = o2.y;
        const int endB = offs[nA + 2];               // offs[N] sentinel

        float aAx = 0.f, aAy = 0.f, aAz = 0.f, aAw = 0.f;
        float aBx = 0.f, aBy = 0.f, aBz = 0.f, aBw = 0.f;

        int ebA = begA, ebB = endA;
        while (ebA < endA || ebB < endB) {
            // one coalesced 16-slot srt load per node (slack past N_EDGES);
            // per-slot sentinel for slots beyond the segment end
            int siA = srt[ebA + sub];
            int siB = srt[ebB + sub];
            siA = (ebA + sub < endA) ? siA : N_NODES;
            siB = (ebB + sub < endB) ? siB : N_NODES;
            const int iA0 = __shfl(siA, goff);
            const int iA1 = __shfl(siA, goff + 1);
            const int iA2 = __shfl(siA, goff + 2);
            const int iA3 = __shfl(siA, goff + 3);
            const int iB0 = __shfl(siB, goff);
            const int iB1 = __shfl(siB, goff + 1);
            const int iB2 = __shfl(siB, goff + 2);
            const int iB3 = __shfl(siB, goff + 3);
            const uint2 vA0 = *(const uint2*)(hbase + (((uint)iA0 << 7) + roff));
            const uint2 vA1 = *(const uint2*)(hbase + (((uint)iA1 << 7) + roff));
            const uint2 vA2 = *(const uint2*)(hbase + (((uint)iA2 << 7) + roff));
            const uint2 vA3 = *(const uint2*)(hbase + (((uint)iA3 << 7) + roff));
            const uint2 vB0 = *(const uint2*)(hbase + (((uint)iB0 << 7) + roff));
            const uint2 vB1 = *(const uint2*)(hbase + (((uint)iB1 << 7) + roff));
            const uint2 vB2 = *(const uint2*)(hbase + (((uint)iB2 << 7) + roff));
            const uint2 vB3 = *(const uint2*)(hbase + (((uint)iB3 << 7) + roff));
            UACC(vA0, aAx, aAy, aAz, aAw);
            UACC(vA1, aAx, aAy, aAz, aAw);
            UACC(vA2, aAx, aAy, aAz, aAw);
            UACC(vA3, aAx, aAy, aAz, aAw);
            UACC(vB0, aBx, aBy, aBz, aBw);
            UACC(vB1, aBx, aBy, aBz, aBw);
            UACC(vB2, aBx, aBy, aBz, aBw);
            UACC(vB3, aBx, aBy, aBz, aBw);
            ebA += 16; ebB += 16;
        }

        // cross-group reduce: after xor16+xor32 every lane holds the full sum
        aAx += __shfl_xor(aAx, 16); aAy += __shfl_xor(aAy, 16);
        aAz += __shfl_xor(aAz, 16); aAw += __shfl_xor(aAw, 16);
        aBx += __shfl_xor(aBx, 16); aBy += __shfl_xor(aBy, 16);
        aBz += __shfl_xor(aBz, 16); aBw += __shfl_xor(aBw, 16);
        aAx += __shfl_xor(aAx, 32); aAy += __shfl_xor(aAy, 32);
        aAz += __shfl_xor(aAz, 32); aAw += __shfl_xor(aAw, 32);
        aBx += __shfl_xor(aBx, 32); aBy += __shfl_xor(aBy, 32);
        aBz += __shfl_xor(aBz, 32); aBw += __shfl_xor(aBw, 32);

        if (g == 0) {
            float4 t; t.x = aAx; t.y = aAy; t.z = aAz; t.w = aAw;
            *((float4*)rbA[wid] + sub) = t;     // lanes 0-15 consecutive: conflict-free
        }
        if (g == 1) {
            float4 t; t.x = aBx; t.y = aBy; t.z = aBz; t.w = aBw;
            *((float4*)rbB[wid] + sub) = t;
        }
        // wave-internal LDS RAW: compiler inserts lgkmcnt wait; no barrier needed

        float oA = bj, oB = bj;
        const float4* ra = (const float4*)rbA[wid];
        const float4* rb = (const float4*)rbB[wid];
#pragma unroll
        for (int k4 = 0; k4 < 16; ++k4) {
            const float4 w  = wrow[k4];          // L1-resident (16KB), per-lane row
            const float4 rA = ra[k4];            // LDS broadcast, conflict-free
            const float4 rB = rb[k4];
            oA += rA.x * w.x + rA.y * w.y + rA.z * w.z + rA.w * w.w;
            oB += rB.x * w.x + rB.y * w.y + rB.z * w.z + rB.w * w.w;
        }
        __builtin_nontemporal_store(oA, out + (ll)nA * D + lane);
        __builtin_nontemporal_store(oB, out + (ll)(nA + 1) * D + lane);
        if (EMIT) {
            outb[(ll)nA * D + lane]       = f2bf(oA);   // plain store: keep L2-hot
            outb[(ll)(nA + 1) * D + lane] = f2bf(oB);
        }
    }
}

extern "C" void kernel_launch(void* const* d_in, const int* in_sizes, int n_in,
                              void* d_out, int out_size, void* d_ws, size_t ws_size,
                              hipStream_t stream) {
    const float* x  = (const float*)d_in[0];   // [N, D]
    const int* edge = (const int*)d_in[1];     // [2, E]: src row then dst row
    const float* W1 = (const float*)d_in[2];   // [D, D]
    const float* b1 = (const float*)d_in[3];   // [D]

    const int* src = edge;
    const int* dst = edge + N_EDGES;

    float* out = (float*)d_out;                    // output 0: [N, D]
    float* hid = (float*)d_out + (ll)N_NODES * D;  // output 1: [N, D]

    // xb (bf16 copy of x, N+1 rows incl zero row) lives in the `out` region:
    // only read during layer 1 (which writes hid); layer 2 overwrites out fully.
    ushort* xb = (ushort*)d_out;                   // 12.81 MB < 25.6 MB

    // workspace layout (~24.7 MiB; 25.6 MB proven available)
    char* ws = (char*)d_ws;
    int* cursor = (int*)ws;  ws += 1024;                                          // [196]
    int* offs   = (int*)ws;  ws += ((size_t)(N_NODES + 1) * 4 + 255) & ~255ull;   // [N+1]
    int* srt    = (int*)ws;  ws += ((size_t)(N_EDGES + SRT_SLACK) * 4 + 255) & ~255ull;
    ushort* hidb = (ushort*)ws; ws += (size_t)(N_NODES + 1) * D * 2;              // [(N+1),D]
    int* tmp    = (int*)ws;                                                       // [196*CAP]

    // ---- build CSR (bucket sort) with cvt overlapped in the same grid ----
    init_kernel<<<1, 256, 0, stream>>>(cursor, offs, xb, hidb);
    bucketA_cvt_kernel<<<PA_BLOCKS + CVT_BLOCKS, 512, 0, stream>>>(src, dst, cursor,
                                                                   tmp, x, xb);
    bucketB_kernel<<<BUCKETS, 512, 0, stream>>>(cursor, tmp, srt, offs);

    // ---- layer 1: hid = segsum(x) @ W1^T + b1 (bf16 gather; emits bf16 hid) ----
    fused_layer<1><<<NBLK, 256, 0, stream>>>(xb, offs, srt, W1, b1, hid, hidb);
    // ---- layer 2: out = segsum(hid) @ W1^T + b1 (bf16 gather) ----
    fused_layer<0><<<NBLK, 256, 0, stream>>>(hidb, offs, srt, W1, b1, out, (ushort*)nullptr);
}